// Round 11
// baseline (427.135 us; speedup 1.0000x reference)
//
#include <hip/hip_runtime.h>
#include <hip/hip_bf16.h>

typedef unsigned short u16;
typedef __attribute__((ext_vector_type(8))) short bf16x8;
typedef __attribute__((ext_vector_type(4))) float f32x4;

#define MFMA(a, b, c) __builtin_amdgcn_mfma_f32_16x16x32_bf16((a), (b), (c), 0, 0, 0)
#define LOG2E 1.4426950408889634f

__device__ __forceinline__ u16 f2b(float f) {  // f32 -> bf16 RNE via HW cvt
  __hip_bfloat16 h = __float2bfloat16(f);
  return __builtin_bit_cast(u16, h);
}
__device__ __forceinline__ float bu2f(u16 u) {
  union { unsigned u; float f; } v; v.u = ((unsigned)u) << 16; return v.f;
}
__device__ __forceinline__ u16 f2bu_sw(float f) {  // software RNE (prep kernels)
  union { float f; unsigned u; } v; v.f = f;
  unsigned r = v.u + 0x7fffu + ((v.u >> 16) & 1u);
  return (u16)(r >> 16);
}
__device__ __forceinline__ int maskcode(int tok, int bd, int bh, int bw) {
  int d = tok / 49, rem = tok - d * 49, hh = rem / 7, w = rem - hh * 7;
  int rd = bd ? (d == 0 ? 1 : 2) : 0;
  int rh = bh ? (hh < 4 ? 1 : 2) : 0;
  int rw = bw ? (w < 4 ? 1 : 2) : 0;
  return rd * 9 + rh * 3 + rw;
}
// token -> global base index (f32 elements) of shifted position for window (id,ih,iw)
__device__ __forceinline__ int tokbase(int tok, int id, int ih, int iw) {
  int d = tok / 49, rem = tok - d * 49, hh = rem / 7, w2 = rem - hh * 7;
  int pd = (id * 2 + d + 1) & 15;
  int ph = ih * 7 + hh + 3; if (ph >= 112) ph -= 112;
  int pw = iw * 7 + w2 + 3; if (pw >= 112) pw -= 112;
  return ((pd * 112 + ph) * 112 + pw) << 7;
}

// ---------- prep: CPB MLP -> bias_tab[507][4] ----------
__global__ void cpb_mlp(const float* __restrict__ w1, const float* __restrict__ b1,
                        const float* __restrict__ w2, float* __restrict__ btab) {
  const int m = blockIdx.x;          // 0..506
  const int k = threadIdx.x;         // 0..511
  const int i0 = m / 169, rm = m % 169, i1 = rm / 13, i2 = rm % 13;
  float c0 = (float)(i0 - 1) * 8.0f;
  float c1 = (float)(i1 - 6) * (8.0f / 6.0f);
  float c2 = (float)(i2 - 6) * (8.0f / 6.0f);
  float t0 = (c0 > 0.f ? 1.f : (c0 < 0.f ? -1.f : 0.f)) * log2f(fabsf(c0) + 1.f) * (1.f / 3.f);
  float t1 = (c1 > 0.f ? 1.f : (c1 < 0.f ? -1.f : 0.f)) * log2f(fabsf(c1) + 1.f) * (1.f / 3.f);
  float t2 = (c2 > 0.f ? 1.f : (c2 < 0.f ? -1.f : 0.f)) * log2f(fabsf(c2) + 1.f) * (1.f / 3.f);
  float hid = fmaxf(w1[k * 3 + 0] * t0 + w1[k * 3 + 1] * t1 + w1[k * 3 + 2] * t2 + b1[k], 0.f);
  __shared__ float red[4][8];
#pragma unroll
  for (int h = 0; h < 4; ++h) {
    float v = hid * w2[h * 512 + k];
    for (int mm = 1; mm < 64; mm <<= 1) v += __shfl_xor(v, mm);
    if ((k & 63) == 0) red[h][k >> 6] = v;
  }
  __syncthreads();
  if (k < 4) {
    float s = 0.f;
#pragma unroll
    for (int j = 0; j < 8; ++j) s += red[k][j];
    btab[m * 4 + k] = s;
  }
}

// ---------- prep: rpb in MFMA fragment layout with mask folded in ----------
// rpbf[combo][h][wv][c][lane][r] f32 ; combo = bd*4+bh*2+bw
__global__ void build_rpbf(const float* __restrict__ btab, float* __restrict__ rpbf) {
  const int total = 8 * 4 * 7 * 7 * 64 * 4;
  int n = blockIdx.x * 256 + threadIdx.x;
  if (n >= total) return;
  int r = n & 3;
  int lane = (n >> 2) & 63;
  int q = n >> 8;                 // combo*196 + h*49 + wv*7 + c
  int c = q % 7;
  int wv = (q / 7) % 7;
  int h = (q / 49) % 4;
  int combo = q / 196;
  int i = 16 * wv + (lane >> 4) * 4 + r;
  int j = 16 * c + (lane & 15);
  float v;
  if (j >= 98) {
    v = -1e30f;
  } else if (i >= 98) {
    v = 0.f;
  } else {
    int di = i / 49, ri = i % 49, hi_ = ri / 7, wi = ri % 7;
    int dj = j / 49, rj = j % 49, hj = rj / 7, wj = rj % 7;
    int idx = (di - dj + 1) * 169 + (hi_ - hj + 6) * 13 + (wi - wj + 6);
    float b = btab[idx * 4 + h];
    v = (16.f / (1.f + expf(-b))) * LOG2E;
    int bd = (combo >> 2) & 1, bh = (combo >> 1) & 1, bw = combo & 1;
    if (maskcode(i, bd, bh, bw) != maskcode(j, bd, bh, bw)) v -= 144.269504f;
  }
  rpbf[n] = v;
}

// ---------- prep: pack qkv weights per head: [h][5blk][32][136] bf16 (q_hi,q_lo,k_hi,k_lo,v_hi)
__global__ void pack_wqkv(const float* __restrict__ qkvw, u16* __restrict__ dst) {
  int bid = blockIdx.x;                       // 640 = 4h * 5blk * 32r
  int h = bid / 160, rem = bid % 160, blk = rem / 32, r = rem % 32;
  int srow = (blk < 2 ? 0 : (blk < 4 ? 128 : 256)) + h * 32 + r;
  bool lo = (blk == 1) || (blk == 3);
  int c = threadIdx.x;                        // 0..135
  float v = (c < 128) ? qkvw[srow * 128 + c] : 0.f;
  u16 hi = f2bu_sw(v);
  u16 outv = lo ? f2bu_sw(v - bu2f(hi)) : hi;
  dst[h * 21760 + blk * 4352 + r * 136 + c] = outv;
}

// ---------- prep: pack proj weights [128][136] bf16 (row c = output col) ----------
__global__ void pack_wproj(const float* __restrict__ pw, u16* __restrict__ dst) {
  int c = blockIdx.x;                         // 0..127
  int m = threadIdx.x;                        // 0..135
  float v = (m < 128) ? pw[c * 128 + m] : 0.f;
  dst[c * 136 + m] = f2bu_sw(v);
}

// ---------- attention kernel: one block per (window, head-PAIR) ----------
// XCD-aware decode: bid = g*16 + hp*8 + s ; win = g*8+s, heads {2hp, 2hp+1} -> all
// blocks of a window share bid%8 == s -> same XCD L2; x gathered ONCE per 2 heads.
// LDS pool 18432 u16 (36864 B) -> 4 blocks/CU:
//   staging: W q/k hi/lo [4][32][136] = 17408 @0  (V weights streamed from L2)
//   ph2/3: Qhi@0, Qlo@4480, Khi@8960, Klo@13440 (each [112][40])
//   ph4: P [112][128] swz @0 ; VT [32][128] swz @14336
#define QHI 0
#define QLO 4480
#define KHI 8960
#define KLO 13440
#define VTB 14336
#define PIDX(i, t) ((i) * 128 + ((t) ^ (((i) & 7) << 3)))
#define VIDX(d, t) (VTB + (d) * 128 + ((t) ^ (((d) & 7) << 3)))

template <bool BF16OUT>
__global__ __launch_bounds__(448, 7) void swin_attn(
    const float* __restrict__ xg, const float* __restrict__ qkvb,
    const float* __restrict__ lscale, const float* __restrict__ rpbf,
    const u16* __restrict__ wqkv, u16* __restrict__ aoutb, float* __restrict__ aoutf) {
  __shared__ u16 lds[18432];
  const int tid = threadIdx.x;
  const int wv = tid >> 6;
  const int l = tid & 63;
  const int l15 = l & 15;
  const int lg = l >> 4;
  const int bid = blockIdx.x;
  const int win = ((bid >> 4) << 3) | (bid & 7);  // XCD-stable window slot
  const int h0 = ((bid >> 3) & 1) << 1;           // head pair {h0, h0+1}
  const int iw = win & 15, ih = (win >> 4) & 15, id = win >> 8;
  const int combo = ((id == 7) << 2) | ((ih == 15) << 1) | (iw == 15);

  // ---- stage q/k weights for h0 (17408 u16 = 2176 uint4) ----
  {
    const uint4* src = (const uint4*)(wqkv + h0 * 21760);
    uint4* dst = (uint4*)lds;
    for (int it = tid; it < 2176; it += 448) dst[it] = src[it];
  }
  // ---- gather own A-row straight to registers, ONCE for both heads ----
  const int arow = 16 * wv + l15;
  bf16x8 xa[4];
  {
    const int base = tokbase((arow < 98) ? arow : 0, id, ih, iw);
    const float* xp = xg + base + lg * 8;
#pragma unroll
    for (int ks = 0; ks < 4; ++ks) {
      const float4 a = *(const float4*)(xp + ks * 32);
      const float4 b4 = *(const float4*)(xp + ks * 32 + 4);
      u16* xo = (u16*)&xa[ks];
      xo[0] = f2b(a.x); xo[1] = f2b(a.y); xo[2] = f2b(a.z); xo[3] = f2b(a.w);
      xo[4] = f2b(b4.x); xo[5] = f2b(b4.y); xo[6] = f2b(b4.z); xo[7] = f2b(b4.w);
    }
  }
  __syncthreads();  // B1: W(h0) staged

  const f32x4 zf = {0.f, 0.f, 0.f, 0.f};
#pragma unroll
  for (int hi = 0; hi < 2; ++hi) {
    const int h = h0 + hi;
    // ---- GEMM1: q,k hi/lo from LDS; v weights streamed from global (L2-hot) ----
    f32x4 aq0 = zf, aq1 = zf, ak0 = zf, ak1 = zf, av0 = zf, av1 = zf;
    const u16* wvb = wqkv + h * 21760 + 17408 + lg * 8;
    bf16x8 bv0 = *(const bf16x8*)(wvb + l15 * 136);
    bf16x8 bv1 = *(const bf16x8*)(wvb + (16 + l15) * 136);
    __builtin_amdgcn_s_setprio(1);
#pragma unroll
    for (int ks = 0; ks < 4; ++ks) {
      const int k0 = ks * 32 + lg * 8;
      bf16x8 nv0, nv1;
      if (ks < 3) {
        nv0 = *(const bf16x8*)(wvb + l15 * 136 + (ks + 1) * 32);
        nv1 = *(const bf16x8*)(wvb + (16 + l15) * 136 + (ks + 1) * 32);
      }
      bf16x8 b;
      b = *(const bf16x8*)(&lds[l15 * 136 + k0]);                aq0 = MFMA(xa[ks], b, aq0);
      b = *(const bf16x8*)(&lds[4352 + l15 * 136 + k0]);         aq0 = MFMA(xa[ks], b, aq0);
      b = *(const bf16x8*)(&lds[(16 + l15) * 136 + k0]);         aq1 = MFMA(xa[ks], b, aq1);
      b = *(const bf16x8*)(&lds[4352 + (16 + l15) * 136 + k0]);  aq1 = MFMA(xa[ks], b, aq1);
      b = *(const bf16x8*)(&lds[8704 + l15 * 136 + k0]);         ak0 = MFMA(xa[ks], b, ak0);
      b = *(const bf16x8*)(&lds[13056 + l15 * 136 + k0]);        ak0 = MFMA(xa[ks], b, ak0);
      b = *(const bf16x8*)(&lds[8704 + (16 + l15) * 136 + k0]);  ak1 = MFMA(xa[ks], b, ak1);
      b = *(const bf16x8*)(&lds[13056 + (16 + l15) * 136 + k0]); ak1 = MFMA(xa[ks], b, ak1);
      av0 = MFMA(xa[ks], bv0, av0);
      av1 = MFMA(xa[ks], bv1, av1);
      if (ks < 3) { bv0 = nv0; bv1 = nv1; }
    }
    __builtin_amdgcn_s_setprio(0);
    __syncthreads();  // B2: W reads done -> pool reusable

    // ---- rpb C-init prefetch (L2 latency hides under phase2 VALU) ----
    const f32x4* rbf = (const f32x4*)rpbf + (((combo * 4 + h) * 7 + wv) * 7) * 64 + l;
    f32x4 att[7];
#pragma unroll
    for (int c = 0; c < 7; ++c) att[c] = rbf[c * 64];

    // ---- phase2: bias, cosine-normalize (scale*log2e folded into q), Q/K stores ----
    const float sc2 = __expf(fminf(lscale[h], 4.60517019f)) * LOG2E;
    const float qb0 = qkvb[h * 32 + l15];
    const float qb1 = qkvb[h * 32 + 16 + l15];
    const float vb0 = qkvb[256 + h * 32 + l15];
    const float vb1 = qkvb[256 + h * 32 + 16 + l15];
#pragma unroll
    for (int r = 0; r < 4; ++r) { aq0[r] += qb0; aq1[r] += qb1; av0[r] += vb0; av1[r] += vb1; }
#pragma unroll
    for (int r = 0; r < 4; ++r) {
      const int row = 16 * wv + lg * 4 + r;
      const bool ok = row < 98;
      float s = aq0[r] * aq0[r] + aq1[r] * aq1[r];
      s += __shfl_xor(s, 1); s += __shfl_xor(s, 2); s += __shfl_xor(s, 4); s += __shfl_xor(s, 8);
      float rn = sc2 * rsqrtf(fmaxf(s, 1e-24f));
      float q0 = ok ? aq0[r] * rn : 0.f, q1 = ok ? aq1[r] * rn : 0.f;
      u16 u0 = f2b(q0), u1 = f2b(q1);
      lds[QHI + row * 40 + l15] = u0;
      lds[QHI + row * 40 + 16 + l15] = u1;
      lds[QLO + row * 40 + l15] = f2b(q0 - bu2f(u0));
      lds[QLO + row * 40 + 16 + l15] = f2b(q1 - bu2f(u1));
      float sk = ak0[r] * ak0[r] + ak1[r] * ak1[r];
      sk += __shfl_xor(sk, 1); sk += __shfl_xor(sk, 2); sk += __shfl_xor(sk, 4); sk += __shfl_xor(sk, 8);
      float rk = rsqrtf(fmaxf(sk, 1e-24f));
      float k0v = ok ? ak0[r] * rk : 0.f, k1v = ok ? ak1[r] * rk : 0.f;
      u16 ku0 = f2b(k0v), ku1 = f2b(k1v);
      lds[KHI + row * 40 + l15] = ku0;
      lds[KHI + row * 40 + 16 + l15] = ku1;
      lds[KLO + row * 40 + l15] = f2b(k0v - bu2f(ku0));
      lds[KLO + row * 40 + 16 + l15] = f2b(k1v - bu2f(ku1));
    }
    __syncthreads();  // B3: Q/K ready

    // ---- phase3: QK^T (3-term) with fragment-layout rpb(+mask) as C-init ----
    const bf16x8 qh = *(const bf16x8*)(&lds[QHI + (16 * wv + l15) * 40 + lg * 8]);
    const bf16x8 qlo = *(const bf16x8*)(&lds[QLO + (16 * wv + l15) * 40 + lg * 8]);
    __builtin_amdgcn_s_setprio(1);
#pragma unroll
    for (int c = 0; c < 7; ++c) {
      const bf16x8 kh = *(const bf16x8*)(&lds[KHI + (16 * c + l15) * 40 + lg * 8]);
      const bf16x8 kl = *(const bf16x8*)(&lds[KLO + (16 * c + l15) * 40 + lg * 8]);
      att[c] = MFMA(qh, kh, att[c]);
      att[c] = MFMA(qlo, kh, att[c]);
      att[c] = MFMA(qh, kl, att[c]);
    }
    __builtin_amdgcn_s_setprio(0);
    float rsv[4];
#pragma unroll
    for (int r = 0; r < 4; ++r) {
      float s = 0.f;
#pragma unroll
      for (int c = 0; c < 7; ++c) { float p = exp2f(att[c][r]); att[c][r] = p; s += p; }
      s += __shfl_xor(s, 1); s += __shfl_xor(s, 2); s += __shfl_xor(s, 4); s += __shfl_xor(s, 8);
      rsv[r] = 1.0f / s;
    }
    __syncthreads();  // B4: Q/K reads done -> P/VT may overlay

    // ---- phase4: write P (normalized, swizzled; pad cols skipped — VT pads are 0
    // and stale LDS content is always finite bf16, so garbage*0 == 0) + V^T ----
#pragma unroll
    for (int r = 0; r < 4; ++r) {
      const int i = 16 * wv + lg * 4 + r;
#pragma unroll
      for (int c = 0; c < 7; ++c) {
        const int t = 16 * c + l15;
        lds[PIDX(i, t)] = f2b(att[c][r] * rsv[r]);
      }
    }
    {
      const int t0 = 16 * wv + lg * 4;
      ushort4 v0, v1;
      v0.x = (t0 + 0 < 98) ? f2b(av0[0]) : (u16)0;
      v0.y = (t0 + 1 < 98) ? f2b(av0[1]) : (u16)0;
      v0.z = (t0 + 2 < 98) ? f2b(av0[2]) : (u16)0;
      v0.w = (t0 + 3 < 98) ? f2b(av0[3]) : (u16)0;
      v1.x = (t0 + 0 < 98) ? f2b(av1[0]) : (u16)0;
      v1.y = (t0 + 1 < 98) ? f2b(av1[1]) : (u16)0;
      v1.z = (t0 + 2 < 98) ? f2b(av1[2]) : (u16)0;
      v1.w = (t0 + 3 < 98) ? f2b(av1[3]) : (u16)0;
      *(ushort4*)(&lds[VIDX(l15, t0)]) = v0;
      *(ushort4*)(&lds[VIDX(16 + l15, t0)]) = v1;
    }
    for (int it = tid; it < 32 * 16; it += 448) {  // zero V^T tok 112..127
      int dd = it >> 4, t = 112 + (it & 15);
      lds[VIDX(dd, t)] = 0;
    }
    __syncthreads();  // B5: P/V^T ready

    // ---- PV TRANSPOSED: D[row=d][col=token] so lane holds 4 consecutive channels ----
    f32x4 o0 = zf, o1 = zf;
    __builtin_amdgcn_s_setprio(1);
#pragma unroll
    for (int ks = 0; ks < 4; ++ks) {
      const int t = ks * 32 + lg * 8;
      const bf16x8 pa = *(const bf16x8*)(&lds[PIDX(16 * wv + l15, t)]);
      const bf16x8 v0f = *(const bf16x8*)(&lds[VIDX(l15, t)]);
      const bf16x8 v1f = *(const bf16x8*)(&lds[VIDX(16 + l15, t)]);
      o0 = MFMA(v0f, pa, o0);   // rows d=lg*4+r (0..15), cols token=16wv+l15
      o1 = MFMA(v1f, pa, o1);   // rows d=16+lg*4+r
    }
    __builtin_amdgcn_s_setprio(0);
    {
      const int tok = 16 * wv + l15;
      if (tok < 98) {
        if (BF16OUT) {
          u16* ab = aoutb + (win * 98 + tok) * 128 + h * 32;
          ushort4 s0, s1;
          s0.x = f2b(o0[0]); s0.y = f2b(o0[1]); s0.z = f2b(o0[2]); s0.w = f2b(o0[3]);
          s1.x = f2b(o1[0]); s1.y = f2b(o1[1]); s1.z = f2b(o1[2]); s1.w = f2b(o1[3]);
          *(ushort4*)(ab + lg * 4) = s0;
          *(ushort4*)(ab + 16 + lg * 4) = s1;
        } else {
          float* ab = aoutf + tokbase(tok, id, ih, iw) + h * 32;
          f32x4 s0 = o0, s1 = o1;
          *(f32x4*)(ab + lg * 4) = s0;
          *(f32x4*)(ab + 16 + lg * 4) = s1;
        }
      }
    }
    // ---- between heads: re-stage W for h0+1 (pool overlaps P/VT) ----
    if (hi == 0) {
      __syncthreads();  // B6: P/VT reads done -> pool reusable for W(h1)
      const uint4* src = (const uint4*)(wqkv + (h0 + 1) * 21760);
      uint4* dst = (uint4*)lds;
      for (int it = tid; it < 2176; it += 448) dst[it] = src[it];
      __syncthreads();  // B1': W(h1) staged
    }
  }
}

// ---------- proj kernel: one block per window, transposed MFMA ----------
template <bool BF16OUT>
__global__ __launch_bounds__(448, 7) void swin_proj(const u16* __restrict__ wp,
                                                    const float* __restrict__ projb,
                                                    const u16* __restrict__ aoutb,
                                                    float* io) {
  __shared__ u16 w[17408];
  __shared__ int tb[98];
  const int tid = threadIdx.x;
  const int wv = tid >> 6;
  const int l = tid & 63;
  const int l15 = l & 15;
  const int lg = l >> 4;
  const int win = blockIdx.x;
  const int iw = win & 15, ih = (win >> 4) & 15, id = win >> 8;
  if (tid < 98) tb[tid] = tokbase(tid, id, ih, iw);
  {
    const uint4* src = (const uint4*)wp;
    uint4* dst = (uint4*)w;
    for (int it = tid; it < 2176; it += 448) dst[it] = src[it];
  }
  __syncthreads();
  const int tok = 16 * wv + l15;
  const int tokc = (tok < 98) ? tok : 97;

  const f32x4 zf = {0.f, 0.f, 0.f, 0.f};
  f32x4 pr[8];
#pragma unroll
  for (int n = 0; n < 8; ++n) pr[n] = zf;
#pragma unroll
  for (int ks = 0; ks < 4; ++ks) {
    bf16x8 oa;  // B-operand: rows = tokens
    if (BF16OUT) {
      oa = *(const bf16x8*)(aoutb + (win * 98 + tokc) * 128 + ks * 32 + lg * 8);
    } else {
      const float* ap = io + tb[tokc] + ks * 32 + lg * 8;
      const float4 f0 = *(const float4*)(ap);
      const float4 f1 = *(const float4*)(ap + 4);
      u16* op = (u16*)&oa;
      op[0] = f2b(f0.x); op[1] = f2b(f0.y); op[2] = f2b(f0.z); op[3] = f2b(f0.w);
      op[4] = f2b(f1.x); op[5] = f2b(f1.y); op[6] = f2b(f1.z); op[7] = f2b(f1.w);
    }
#pragma unroll
    for (int n = 0; n < 8; ++n) {
      const bf16x8 wbf = *(const bf16x8*)(&w[(16 * n + l15) * 136 + ks * 32 + lg * 8]);
      pr[n] = MFMA(wbf, oa, pr[n]);  // rows = outcols 16n+lg*4+r, cols = token l15
    }
  }
  // store: lane holds 4 consecutive outcols of its token -> float4 scatter per row
#pragma unroll
  for (int n = 0; n < 8; ++n) {
    const float4 pb4 = *(const float4*)(projb + 16 * n + lg * 4);
    f32x4 o = pr[n];
    o[0] += pb4.x; o[1] += pb4.y; o[2] += pb4.z; o[3] += pb4.w;
    if (tok < 98) *(f32x4*)(io + tb[tok] + 16 * n + lg * 4) = o;
  }
}

extern "C" void kernel_launch(void* const* d_in, const int* in_sizes, int n_in,
                              void* d_out, int out_size, void* d_ws, size_t ws_size,
                              hipStream_t stream) {
  const float* xg = (const float*)d_in[0];
  const float* qkvw = (const float*)d_in[1];
  const float* qkvb = (const float*)d_in[2];
  const float* projw = (const float*)d_in[3];
  const float* projb = (const float*)d_in[4];
  const float* lsc = (const float*)d_in[5];
  const float* w1 = (const float*)d_in[6];
  const float* b1 = (const float*)d_in[7];
  const float* w2 = (const float*)d_in[8];

  char* ws = (char*)d_ws;
  float* btab = (float*)(ws);             // 8,112 B
  u16* wq = (u16*)(ws + 8192);            // 174,080 B -> ends 182,272
  u16* wp = (u16*)(ws + 182272);          // 34,816 B  -> ends 217,088
  float* rpbf = (float*)(ws + 217088);    // 1,605,632 B -> ends 1,822,720
  u16* aoutb = (u16*)(ws + 1822720);      // 51,380,224 B -> ends 53,202,944
  float* io = (float*)d_out;

  const bool bf16path = ws_size >= (size_t)53202944;

  cpb_mlp<<<507, 512, 0, stream>>>(w1, b1, w2, btab);
  build_rpbf<<<(8 * 4 * 7 * 7 * 64 * 4 + 255) / 256, 256, 0, stream>>>(btab, rpbf);
  pack_wqkv<<<640, 136, 0, stream>>>(qkvw, wq);
  pack_wproj<<<128, 136, 0, stream>>>(projw, wp);
  if (bf16path) {
    swin_attn<true><<<4096, 448, 0, stream>>>(xg, qkvb, lsc, rpbf, wq, aoutb, io);
    swin_proj<true><<<2048, 448, 0, stream>>>(wp, projb, aoutb, io);
  } else {
    swin_attn<false><<<4096, 448, 0, stream>>>(xg, qkvb, lsc, rpbf, wq, nullptr, io);
    swin_proj<false><<<2048, 448, 0, stream>>>(wp, projb, nullptr, io);
  }
}

// Round 12
// 296.738 us; speedup vs baseline: 1.4394x; 1.4394x over previous
//
#include <hip/hip_runtime.h>
#include <hip/hip_bf16.h>

typedef unsigned short u16;
typedef __attribute__((ext_vector_type(8))) short bf16x8;
typedef __attribute__((ext_vector_type(4))) float f32x4;

#define MFMA(a, b, c) __builtin_amdgcn_mfma_f32_16x16x32_bf16((a), (b), (c), 0, 0, 0)
#define LOG2E 1.4426950408889634f

__device__ __forceinline__ u16 f2b(float f) {  // f32 -> bf16 RNE via HW cvt
  __hip_bfloat16 h = __float2bfloat16(f);
  return __builtin_bit_cast(u16, h);
}
__device__ __forceinline__ float bu2f(u16 u) {
  union { unsigned u; float f; } v; v.u = ((unsigned)u) << 16; return v.f;
}
__device__ __forceinline__ u16 f2bu_sw(float f) {  // software RNE (prep kernels)
  union { float f; unsigned u; } v; v.f = f;
  unsigned r = v.u + 0x7fffu + ((v.u >> 16) & 1u);
  return (u16)(r >> 16);
}
__device__ __forceinline__ int maskcode(int tok, int bd, int bh, int bw) {
  int d = tok / 49, rem = tok - d * 49, hh = rem / 7, w = rem - hh * 7;
  int rd = bd ? (d == 0 ? 1 : 2) : 0;
  int rh = bh ? (hh < 4 ? 1 : 2) : 0;
  int rw = bw ? (w < 4 ? 1 : 2) : 0;
  return rd * 9 + rh * 3 + rw;
}
// token -> global base index (f32 elements) of shifted position for window (id,ih,iw)
__device__ __forceinline__ int tokbase(int tok, int id, int ih, int iw) {
  int d = tok / 49, rem = tok - d * 49, hh = rem / 7, w2 = rem - hh * 7;
  int pd = (id * 2 + d + 1) & 15;
  int ph = ih * 7 + hh + 3; if (ph >= 112) ph -= 112;
  int pw = iw * 7 + w2 + 3; if (pw >= 112) pw -= 112;
  return ((pd * 112 + ph) * 112 + pw) << 7;
}

// ---------- prep: CPB MLP -> bias_tab[507][4] ----------
__global__ void cpb_mlp(const float* __restrict__ w1, const float* __restrict__ b1,
                        const float* __restrict__ w2, float* __restrict__ btab) {
  const int m = blockIdx.x;          // 0..506
  const int k = threadIdx.x;         // 0..511
  const int i0 = m / 169, rm = m % 169, i1 = rm / 13, i2 = rm % 13;
  float c0 = (float)(i0 - 1) * 8.0f;
  float c1 = (float)(i1 - 6) * (8.0f / 6.0f);
  float c2 = (float)(i2 - 6) * (8.0f / 6.0f);
  float t0 = (c0 > 0.f ? 1.f : (c0 < 0.f ? -1.f : 0.f)) * log2f(fabsf(c0) + 1.f) * (1.f / 3.f);
  float t1 = (c1 > 0.f ? 1.f : (c1 < 0.f ? -1.f : 0.f)) * log2f(fabsf(c1) + 1.f) * (1.f / 3.f);
  float t2 = (c2 > 0.f ? 1.f : (c2 < 0.f ? -1.f : 0.f)) * log2f(fabsf(c2) + 1.f) * (1.f / 3.f);
  float hid = fmaxf(w1[k * 3 + 0] * t0 + w1[k * 3 + 1] * t1 + w1[k * 3 + 2] * t2 + b1[k], 0.f);
  __shared__ float red[4][8];
#pragma unroll
  for (int h = 0; h < 4; ++h) {
    float v = hid * w2[h * 512 + k];
    for (int mm = 1; mm < 64; mm <<= 1) v += __shfl_xor(v, mm);
    if ((k & 63) == 0) red[h][k >> 6] = v;
  }
  __syncthreads();
  if (k < 4) {
    float s = 0.f;
#pragma unroll
    for (int j = 0; j < 8; ++j) s += red[k][j];
    btab[m * 4 + k] = s;
  }
}

// ---------- prep: rpb in MFMA fragment layout with mask folded in ----------
// rpbf[combo][h][wv][c][lane][r] f32 ; combo = bd*4+bh*2+bw
__global__ void build_rpbf(const float* __restrict__ btab, float* __restrict__ rpbf) {
  const int total = 8 * 4 * 7 * 7 * 64 * 4;
  int n = blockIdx.x * 256 + threadIdx.x;
  if (n >= total) return;
  int r = n & 3;
  int lane = (n >> 2) & 63;
  int q = n >> 8;                 // combo*196 + h*49 + wv*7 + c
  int c = q % 7;
  int wv = (q / 7) % 7;
  int h = (q / 49) % 4;
  int combo = q / 196;
  int i = 16 * wv + (lane >> 4) * 4 + r;
  int j = 16 * c + (lane & 15);
  float v;
  if (j >= 98) {
    v = -1e30f;
  } else if (i >= 98) {
    v = 0.f;
  } else {
    int di = i / 49, ri = i % 49, hi_ = ri / 7, wi = ri % 7;
    int dj = j / 49, rj = j % 49, hj = rj / 7, wj = rj % 7;
    int idx = (di - dj + 1) * 169 + (hi_ - hj + 6) * 13 + (wi - wj + 6);
    float b = btab[idx * 4 + h];
    v = (16.f / (1.f + expf(-b))) * LOG2E;
    int bd = (combo >> 2) & 1, bh = (combo >> 1) & 1, bw = combo & 1;
    if (maskcode(i, bd, bh, bw) != maskcode(j, bd, bh, bw)) v -= 144.269504f;
  }
  rpbf[n] = v;
}

// ---------- prep: pack qkv weights per head: [h][5blk][32][136] bf16 (q_hi,q_lo,k_hi,k_lo,v_hi)
__global__ void pack_wqkv(const float* __restrict__ qkvw, u16* __restrict__ dst) {
  int bid = blockIdx.x;                       // 640 = 4h * 5blk * 32r
  int h = bid / 160, rem = bid % 160, blk = rem / 32, r = rem % 32;
  int srow = (blk < 2 ? 0 : (blk < 4 ? 128 : 256)) + h * 32 + r;
  bool lo = (blk == 1) || (blk == 3);
  int c = threadIdx.x;                        // 0..135
  float v = (c < 128) ? qkvw[srow * 128 + c] : 0.f;
  u16 hi = f2bu_sw(v);
  u16 outv = lo ? f2bu_sw(v - bu2f(hi)) : hi;
  dst[h * 21760 + blk * 4352 + r * 136 + c] = outv;
}

// ---------- prep: pack proj weights [128][136] bf16 (row c = output col) ----------
__global__ void pack_wproj(const float* __restrict__ pw, u16* __restrict__ dst) {
  int c = blockIdx.x;                         // 0..127
  int m = threadIdx.x;                        // 0..135
  float v = (m < 128) ? pw[c * 128 + m] : 0.f;
  dst[c * 136 + m] = f2bu_sw(v);
}

// ---------- attention kernel: one block per (window, head) ----------
// XCD-aware decode: bid = g*32 + h*8 + s ; win = g*8+s, head = h -> all 4 heads of a
// window land on the same XCD (bid % 8 == s), sharing x in that XCD's L2.
// LDS pool 18432 u16 (36864 B) -> 4 blocks/CU:
//   phase1: staged W q/k hi/lo [4][32][136] = 17408 @0  (V weights streamed from L2)
//   phase2/3: Qhi@0, Qlo@4480, Khi@8960, Klo@13440 (each [112][40])
//   phase4: P [112][128] swz @0 ; VT [32][128] swz @14336
#define QHI 0
#define QLO 4480
#define KHI 8960
#define KLO 13440
#define VTB 14336
#define PIDX(i, t) ((i) * 128 + ((t) ^ (((i) & 7) << 3)))
#define VIDX(d, t) (VTB + (d) * 128 + ((t) ^ (((d) & 7) << 3)))

template <bool BF16OUT>
__global__ __launch_bounds__(448, 7) void swin_attn(
    const float* __restrict__ xg, const float* __restrict__ qkvb,
    const float* __restrict__ lscale, const float* __restrict__ rpbf,
    const u16* __restrict__ wqkv, u16* __restrict__ aoutb, float* __restrict__ aoutf) {
  __shared__ u16 lds[18432];
  const int tid = threadIdx.x;
  const int wv = tid >> 6;
  const int l = tid & 63;
  const int l15 = l & 15;
  const int lg = l >> 4;
  const int bid = blockIdx.x;
  const int win = ((bid >> 5) << 3) | (bid & 7);  // XCD-stable window slot
  const int h = (bid >> 3) & 3;
  const int iw = win & 15, ih = (win >> 4) & 15, id = win >> 8;
  const int combo = ((id == 7) << 2) | ((ih == 15) << 1) | (iw == 15);

  // ---- T14 async-stage: ISSUE W loads first (latency hides under x-gather) ----
  uint4 wreg[5];
  {
    const uint4* src = (const uint4*)(wqkv + h * 21760);
#pragma unroll
    for (int i = 0; i < 5; ++i) {
      const int it = tid + i * 448;
      if (it < 2176) wreg[i] = src[it];
    }
  }
  // ---- gather own A-row straight to registers (branchless; pad rows clamp to row 0) ----
  const int arow = 16 * wv + l15;
  bf16x8 xa[4];
  {
    const int base = tokbase((arow < 98) ? arow : 0, id, ih, iw);
    const float* xp = xg + base + lg * 8;
#pragma unroll
    for (int ks = 0; ks < 4; ++ks) {
      const float4 a = *(const float4*)(xp + ks * 32);
      const float4 b4 = *(const float4*)(xp + ks * 32 + 4);
      u16* xo = (u16*)&xa[ks];
      xo[0] = f2b(a.x); xo[1] = f2b(a.y); xo[2] = f2b(a.z); xo[3] = f2b(a.w);
      xo[4] = f2b(b4.x); xo[5] = f2b(b4.y); xo[6] = f2b(b4.z); xo[7] = f2b(b4.w);
    }
  }
  // ---- issue first V-weight tiles before the barrier (overlap barrier drain) ----
  const u16* wvb = wqkv + h * 21760 + 17408 + lg * 8;
  bf16x8 bv0 = *(const bf16x8*)(wvb + l15 * 136);
  bf16x8 bv1 = *(const bf16x8*)(wvb + (16 + l15) * 136);
  // ---- WRITE W to LDS (loads have had ~200+ cyc to land) ----
  {
    uint4* dst = (uint4*)lds;
#pragma unroll
    for (int i = 0; i < 5; ++i) {
      const int it = tid + i * 448;
      if (it < 2176) dst[it] = wreg[i];
    }
  }
  __syncthreads();  // B1: weights staged

  // ---- GEMM1: q,k hi/lo from LDS; v weights streamed from global (L2-hot) ----
  const f32x4 zf = {0.f, 0.f, 0.f, 0.f};
  f32x4 aq0 = zf, aq1 = zf, ak0 = zf, ak1 = zf, av0 = zf, av1 = zf;
  __builtin_amdgcn_s_setprio(1);
#pragma unroll
  for (int ks = 0; ks < 4; ++ks) {
    const int k0 = ks * 32 + lg * 8;
    bf16x8 nv0, nv1;
    if (ks < 3) {
      nv0 = *(const bf16x8*)(wvb + l15 * 136 + (ks + 1) * 32);
      nv1 = *(const bf16x8*)(wvb + (16 + l15) * 136 + (ks + 1) * 32);
    }
    bf16x8 b;
    b = *(const bf16x8*)(&lds[l15 * 136 + k0]);                aq0 = MFMA(xa[ks], b, aq0);
    b = *(const bf16x8*)(&lds[4352 + l15 * 136 + k0]);         aq0 = MFMA(xa[ks], b, aq0);
    b = *(const bf16x8*)(&lds[(16 + l15) * 136 + k0]);         aq1 = MFMA(xa[ks], b, aq1);
    b = *(const bf16x8*)(&lds[4352 + (16 + l15) * 136 + k0]);  aq1 = MFMA(xa[ks], b, aq1);
    b = *(const bf16x8*)(&lds[8704 + l15 * 136 + k0]);         ak0 = MFMA(xa[ks], b, ak0);
    b = *(const bf16x8*)(&lds[13056 + l15 * 136 + k0]);        ak0 = MFMA(xa[ks], b, ak0);
    b = *(const bf16x8*)(&lds[8704 + (16 + l15) * 136 + k0]);  ak1 = MFMA(xa[ks], b, ak1);
    b = *(const bf16x8*)(&lds[13056 + (16 + l15) * 136 + k0]); ak1 = MFMA(xa[ks], b, ak1);
    av0 = MFMA(xa[ks], bv0, av0);
    av1 = MFMA(xa[ks], bv1, av1);
    if (ks < 3) { bv0 = nv0; bv1 = nv1; }
  }
  __builtin_amdgcn_s_setprio(0);
  __syncthreads();  // B2: weight reads done -> pool reusable

  // ---- rpb C-init prefetch (L2 latency hides under phase2 VALU) ----
  const f32x4* rbf = (const f32x4*)rpbf + (((combo * 4 + h) * 7 + wv) * 7) * 64 + l;
  f32x4 att[7];
#pragma unroll
  for (int c = 0; c < 7; ++c) att[c] = rbf[c * 64];

  // ---- phase2: bias, cosine-normalize (scale*log2e folded into q), Q/K stores ----
  const float sc2 = __expf(fminf(lscale[h], 4.60517019f)) * LOG2E;
  const float qb0 = qkvb[h * 32 + l15];
  const float qb1 = qkvb[h * 32 + 16 + l15];
  const float vb0 = qkvb[256 + h * 32 + l15];
  const float vb1 = qkvb[256 + h * 32 + 16 + l15];
#pragma unroll
  for (int r = 0; r < 4; ++r) { aq0[r] += qb0; aq1[r] += qb1; av0[r] += vb0; av1[r] += vb1; }
#pragma unroll
  for (int r = 0; r < 4; ++r) {
    const int row = 16 * wv + lg * 4 + r;
    const bool ok = row < 98;
    float s = aq0[r] * aq0[r] + aq1[r] * aq1[r];
    s += __shfl_xor(s, 1); s += __shfl_xor(s, 2); s += __shfl_xor(s, 4); s += __shfl_xor(s, 8);
    float rn = sc2 * rsqrtf(fmaxf(s, 1e-24f));
    float q0 = ok ? aq0[r] * rn : 0.f, q1 = ok ? aq1[r] * rn : 0.f;
    u16 u0 = f2b(q0), u1 = f2b(q1);
    lds[QHI + row * 40 + l15] = u0;
    lds[QHI + row * 40 + 16 + l15] = u1;
    lds[QLO + row * 40 + l15] = f2b(q0 - bu2f(u0));
    lds[QLO + row * 40 + 16 + l15] = f2b(q1 - bu2f(u1));
    float sk = ak0[r] * ak0[r] + ak1[r] * ak1[r];
    sk += __shfl_xor(sk, 1); sk += __shfl_xor(sk, 2); sk += __shfl_xor(sk, 4); sk += __shfl_xor(sk, 8);
    float rk = rsqrtf(fmaxf(sk, 1e-24f));
    float k0v = ok ? ak0[r] * rk : 0.f, k1v = ok ? ak1[r] * rk : 0.f;
    u16 ku0 = f2b(k0v), ku1 = f2b(k1v);
    lds[KHI + row * 40 + l15] = ku0;
    lds[KHI + row * 40 + 16 + l15] = ku1;
    lds[KLO + row * 40 + l15] = f2b(k0v - bu2f(ku0));
    lds[KLO + row * 40 + 16 + l15] = f2b(k1v - bu2f(ku1));
  }
  __syncthreads();  // B3: Q/K ready

  // ---- phase3: QK^T (3-term) with fragment-layout rpb(+mask) as C-init ----
  const bf16x8 qh = *(const bf16x8*)(&lds[QHI + (16 * wv + l15) * 40 + lg * 8]);
  const bf16x8 qlo = *(const bf16x8*)(&lds[QLO + (16 * wv + l15) * 40 + lg * 8]);
  __builtin_amdgcn_s_setprio(1);
#pragma unroll
  for (int c = 0; c < 7; ++c) {
    const bf16x8 kh = *(const bf16x8*)(&lds[KHI + (16 * c + l15) * 40 + lg * 8]);
    const bf16x8 kl = *(const bf16x8*)(&lds[KLO + (16 * c + l15) * 40 + lg * 8]);
    att[c] = MFMA(qh, kh, att[c]);
    att[c] = MFMA(qlo, kh, att[c]);
    att[c] = MFMA(qh, kl, att[c]);
  }
  __builtin_amdgcn_s_setprio(0);
  float rsv[4];
#pragma unroll
  for (int r = 0; r < 4; ++r) {
    float s = 0.f;
#pragma unroll
    for (int c = 0; c < 7; ++c) { float p = exp2f(att[c][r]); att[c][r] = p; s += p; }
    s += __shfl_xor(s, 1); s += __shfl_xor(s, 2); s += __shfl_xor(s, 4); s += __shfl_xor(s, 8);
    rsv[r] = 1.0f / s;
  }
  __syncthreads();  // B4: Q/K reads done -> P/VT may overlay

  // ---- phase4: write P (normalized, swizzled; pad cols skipped — VT pads are 0
  // and stale LDS content is always finite bf16, so garbage*0 == 0) + V^T ----
#pragma unroll
  for (int r = 0; r < 4; ++r) {
    const int i = 16 * wv + lg * 4 + r;
#pragma unroll
    for (int c = 0; c < 7; ++c) {
      const int t = 16 * c + l15;
      lds[PIDX(i, t)] = f2b(att[c][r] * rsv[r]);
    }
  }
  {
    const int t0 = 16 * wv + lg * 4;
    ushort4 v0, v1;
    v0.x = (t0 + 0 < 98) ? f2b(av0[0]) : (u16)0;
    v0.y = (t0 + 1 < 98) ? f2b(av0[1]) : (u16)0;
    v0.z = (t0 + 2 < 98) ? f2b(av0[2]) : (u16)0;
    v0.w = (t0 + 3 < 98) ? f2b(av0[3]) : (u16)0;
    v1.x = (t0 + 0 < 98) ? f2b(av1[0]) : (u16)0;
    v1.y = (t0 + 1 < 98) ? f2b(av1[1]) : (u16)0;
    v1.z = (t0 + 2 < 98) ? f2b(av1[2]) : (u16)0;
    v1.w = (t0 + 3 < 98) ? f2b(av1[3]) : (u16)0;
    *(ushort4*)(&lds[VIDX(l15, t0)]) = v0;
    *(ushort4*)(&lds[VIDX(16 + l15, t0)]) = v1;
  }
  for (int it = tid; it < 32 * 16; it += 448) {  // zero V^T tok 112..127
    int dd = it >> 4, t = 112 + (it & 15);
    lds[VIDX(dd, t)] = 0;
  }
  __syncthreads();  // B5: P/V^T ready

  // ---- PV TRANSPOSED: D[row=d][col=token] so lane holds 4 consecutive channels ----
  f32x4 o0 = zf, o1 = zf;
  __builtin_amdgcn_s_setprio(1);
#pragma unroll
  for (int ks = 0; ks < 4; ++ks) {
    const int t = ks * 32 + lg * 8;
    const bf16x8 pa = *(const bf16x8*)(&lds[PIDX(16 * wv + l15, t)]);
    const bf16x8 v0f = *(const bf16x8*)(&lds[VIDX(l15, t)]);
    const bf16x8 v1f = *(const bf16x8*)(&lds[VIDX(16 + l15, t)]);
    o0 = MFMA(v0f, pa, o0);   // rows d=lg*4+r (0..15), cols token=16wv+l15
    o1 = MFMA(v1f, pa, o1);   // rows d=16+lg*4+r
  }
  __builtin_amdgcn_s_setprio(0);
  {
    const int tok = 16 * wv + l15;
    if (tok < 98) {
      if (BF16OUT) {
        u16* ab = aoutb + (win * 98 + tok) * 128 + h * 32;
        ushort4 s0, s1;
        s0.x = f2b(o0[0]); s0.y = f2b(o0[1]); s0.z = f2b(o0[2]); s0.w = f2b(o0[3]);
        s1.x = f2b(o1[0]); s1.y = f2b(o1[1]); s1.z = f2b(o1[2]); s1.w = f2b(o1[3]);
        *(ushort4*)(ab + lg * 4) = s0;
        *(ushort4*)(ab + 16 + lg * 4) = s1;
      } else {
        float* ab = aoutf + tokbase(tok, id, ih, iw) + h * 32;
        f32x4 s0 = o0, s1 = o1;
        *(f32x4*)(ab + lg * 4) = s0;
        *(f32x4*)(ab + 16 + lg * 4) = s1;
      }
    }
  }
}

// ---------- proj kernel: one block per window, transposed MFMA ----------
template <bool BF16OUT>
__global__ __launch_bounds__(448, 7) void swin_proj(const u16* __restrict__ wp,
                                                    const float* __restrict__ projb,
                                                    const u16* __restrict__ aoutb,
                                                    float* io) {
  __shared__ u16 w[17408];
  __shared__ int tb[98];
  const int tid = threadIdx.x;
  const int wv = tid >> 6;
  const int l = tid & 63;
  const int l15 = l & 15;
  const int lg = l >> 4;
  const int win = blockIdx.x;
  const int iw = win & 15, ih = (win >> 4) & 15, id = win >> 8;
  // T14 split: issue loads, compute tb between, then write
  uint4 wreg[5];
  {
    const uint4* src = (const uint4*)wp;
#pragma unroll
    for (int i = 0; i < 5; ++i) {
      const int it = tid + i * 448;
      if (it < 2176) wreg[i] = src[it];
    }
  }
  if (tid < 98) tb[tid] = tokbase(tid, id, ih, iw);
  {
    uint4* dst = (uint4*)w;
#pragma unroll
    for (int i = 0; i < 5; ++i) {
      const int it = tid + i * 448;
      if (it < 2176) dst[it] = wreg[i];
    }
  }
  __syncthreads();
  const int tok = 16 * wv + l15;
  const int tokc = (tok < 98) ? tok : 97;

  const f32x4 zf = {0.f, 0.f, 0.f, 0.f};
  f32x4 pr[8];
#pragma unroll
  for (int n = 0; n < 8; ++n) pr[n] = zf;
#pragma unroll
  for (int ks = 0; ks < 4; ++ks) {
    bf16x8 oa;  // B-operand: rows = tokens
    if (BF16OUT) {
      oa = *(const bf16x8*)(aoutb + (win * 98 + tokc) * 128 + ks * 32 + lg * 8);
    } else {
      const float* ap = io + tb[tokc] + ks * 32 + lg * 8;
      const float4 f0 = *(const float4*)(ap);
      const float4 f1 = *(const float4*)(ap + 4);
      u16* op = (u16*)&oa;
      op[0] = f2b(f0.x); op[1] = f2b(f0.y); op[2] = f2b(f0.z); op[3] = f2b(f0.w);
      op[4] = f2b(f1.x); op[5] = f2b(f1.y); op[6] = f2b(f1.z); op[7] = f2b(f1.w);
    }
#pragma unroll
    for (int n = 0; n < 8; ++n) {
      const bf16x8 wbf = *(const bf16x8*)(&w[(16 * n + l15) * 136 + ks * 32 + lg * 8]);
      pr[n] = MFMA(wbf, oa, pr[n]);  // rows = outcols 16n+lg*4+r, cols = token l15
    }
  }
  // store: lane holds 4 consecutive outcols of its token -> float4 scatter per row
#pragma unroll
  for (int n = 0; n < 8; ++n) {
    const float4 pb4 = *(const float4*)(projb + 16 * n + lg * 4);
    f32x4 o = pr[n];
    o[0] += pb4.x; o[1] += pb4.y; o[2] += pb4.z; o[3] += pb4.w;
    if (tok < 98) *(f32x4*)(io + tb[tok] + 16 * n + lg * 4) = o;
  }
}

extern "C" void kernel_launch(void* const* d_in, const int* in_sizes, int n_in,
                              void* d_out, int out_size, void* d_ws, size_t ws_size,
                              hipStream_t stream) {
  const float* xg = (const float*)d_in[0];
  const float* qkvw = (const float*)d_in[1];
  const float* qkvb = (const float*)d_in[2];
  const float* projw = (const float*)d_in[3];
  const float* projb = (const float*)d_in[4];
  const float* lsc = (const float*)d_in[5];
  const float* w1 = (const float*)d_in[6];
  const float* b1 = (const float*)d_in[7];
  const float* w2 = (const float*)d_in[8];

  char* ws = (char*)d_ws;
  float* btab = (float*)(ws);             // 8,112 B
  u16* wq = (u16*)(ws + 8192);            // 174,080 B -> ends 182,272
  u16* wp = (u16*)(ws + 182272);          // 34,816 B  -> ends 217,088
  float* rpbf = (float*)(ws + 217088);    // 1,605,632 B -> ends 1,822,720
  u16* aoutb = (u16*)(ws + 1822720);      // 51,380,224 B -> ends 53,202,944
  float* io = (float*)d_out;

  const bool bf16path = ws_size >= (size_t)53202944;

  cpb_mlp<<<507, 512, 0, stream>>>(w1, b1, w2, btab);
  build_rpbf<<<(8 * 4 * 7 * 7 * 64 * 4 + 255) / 256, 256, 0, stream>>>(btab, rpbf);
  pack_wqkv<<<640, 136, 0, stream>>>(qkvw, wq);
  pack_wproj<<<128, 136, 0, stream>>>(projw, wp);
  if (bf16path) {
    swin_attn<true><<<8192, 448, 0, stream>>>(xg, qkvb, lsc, rpbf, wq, aoutb, io);
    swin_proj<true><<<2048, 448, 0, stream>>>(wp, projb, aoutb, io);
  } else {
    swin_attn<false><<<8192, 448, 0, stream>>>(xg, qkvb, lsc, rpbf, wq, nullptr, io);
    swin_proj<false><<<2048, 448, 0, stream>>>(wp, projb, nullptr, io);
  }
}

// Round 13
// 179.561 us; speedup vs baseline: 2.3788x; 1.6526x over previous
//
#include <hip/hip_runtime.h>
#include <hip/hip_bf16.h>

typedef unsigned short u16;
typedef __attribute__((ext_vector_type(8))) short bf16x8;
typedef __attribute__((ext_vector_type(4))) float f32x4;

#define MFMA(a, b, c) __builtin_amdgcn_mfma_f32_16x16x32_bf16((a), (b), (c), 0, 0, 0)
#define LOG2E 1.4426950408889634f

__device__ __forceinline__ u16 f2b(float f) {  // f32 -> bf16 RNE via HW cvt
  __hip_bfloat16 h = __float2bfloat16(f);
  return __builtin_bit_cast(u16, h);
}
__device__ __forceinline__ float bu2f(u16 u) {
  union { unsigned u; float f; } v; v.u = ((unsigned)u) << 16; return v.f;
}
__device__ __forceinline__ u16 f2bu_sw(float f) {  // software RNE (prep kernels)
  union { float f; unsigned u; } v; v.f = f;
  unsigned r = v.u + 0x7fffu + ((v.u >> 16) & 1u);
  return (u16)(r >> 16);
}
__device__ __forceinline__ int maskcode(int tok, int bd, int bh, int bw) {
  int d = tok / 49, rem = tok - d * 49, hh = rem / 7, w = rem - hh * 7;
  int rd = bd ? (d == 0 ? 1 : 2) : 0;
  int rh = bh ? (hh < 4 ? 1 : 2) : 0;
  int rw = bw ? (w < 4 ? 1 : 2) : 0;
  return rd * 9 + rh * 3 + rw;
}
// token -> global base index (f32 elements) of shifted position for window (id,ih,iw)
__device__ __forceinline__ int tokbase(int tok, int id, int ih, int iw) {
  int d = tok / 49, rem = tok - d * 49, hh = rem / 7, w2 = rem - hh * 7;
  int pd = (id * 2 + d + 1) & 15;
  int ph = ih * 7 + hh + 3; if (ph >= 112) ph -= 112;
  int pw = iw * 7 + w2 + 3; if (pw >= 112) pw -= 112;
  return ((pd * 112 + ph) * 112 + pw) << 7;
}

// ---------- prep: CPB MLP -> bias_tab[507][4] ----------
__global__ void cpb_mlp(const float* __restrict__ w1, const float* __restrict__ b1,
                        const float* __restrict__ w2, float* __restrict__ btab) {
  const int m = blockIdx.x;          // 0..506
  const int k = threadIdx.x;         // 0..511
  const int i0 = m / 169, rm = m % 169, i1 = rm / 13, i2 = rm % 13;
  float c0 = (float)(i0 - 1) * 8.0f;
  float c1 = (float)(i1 - 6) * (8.0f / 6.0f);
  float c2 = (float)(i2 - 6) * (8.0f / 6.0f);
  float t0 = (c0 > 0.f ? 1.f : (c0 < 0.f ? -1.f : 0.f)) * log2f(fabsf(c0) + 1.f) * (1.f / 3.f);
  float t1 = (c1 > 0.f ? 1.f : (c1 < 0.f ? -1.f : 0.f)) * log2f(fabsf(c1) + 1.f) * (1.f / 3.f);
  float t2 = (c2 > 0.f ? 1.f : (c2 < 0.f ? -1.f : 0.f)) * log2f(fabsf(c2) + 1.f) * (1.f / 3.f);
  float hid = fmaxf(w1[k * 3 + 0] * t0 + w1[k * 3 + 1] * t1 + w1[k * 3 + 2] * t2 + b1[k], 0.f);
  __shared__ float red[4][8];
#pragma unroll
  for (int h = 0; h < 4; ++h) {
    float v = hid * w2[h * 512 + k];
    for (int mm = 1; mm < 64; mm <<= 1) v += __shfl_xor(v, mm);
    if ((k & 63) == 0) red[h][k >> 6] = v;
  }
  __syncthreads();
  if (k < 4) {
    float s = 0.f;
#pragma unroll
    for (int j = 0; j < 8; ++j) s += red[k][j];
    btab[m * 4 + k] = s;
  }
}

// ---------- prep: rpb in TRANSPOSED MFMA fragment layout with mask folded in ----------
// rpbf[combo][h][wv][c][lane][r] f32 ; value for D[tokK][tokQ] fragment:
//   tokK = 16c + (lane>>4)*4 + r ; tokQ = 16wv + (lane&15)
__global__ void build_rpbf(const float* __restrict__ btab, float* __restrict__ rpbf) {
  const int total = 8 * 4 * 7 * 7 * 64 * 4;
  int n = blockIdx.x * 256 + threadIdx.x;
  if (n >= total) return;
  int r = n & 3;
  int lane = (n >> 2) & 63;
  int q = n >> 8;                 // combo*196 + h*49 + wv*7 + c
  int c = q % 7;
  int wv = (q / 7) % 7;
  int h = (q / 49) % 4;
  int combo = q / 196;
  int tokK = 16 * c + (lane >> 4) * 4 + r;
  int tokQ = 16 * wv + (lane & 15);
  float v;
  if (tokK >= 98) {
    v = -1e30f;                   // pad keys must vanish in softmax
  } else if (tokQ >= 98) {
    v = 0.f;                      // pad queries are masked at store
  } else {
    int dq = tokQ / 49, rq = tokQ % 49, hq = rq / 7, wq = rq % 7;
    int dk = tokK / 49, rk = tokK % 49, hk = rk / 7, wk = rk % 7;
    int idx = (dq - dk + 1) * 169 + (hq - hk + 6) * 13 + (wq - wk + 6);
    float b = btab[idx * 4 + h];
    v = (16.f / (1.f + expf(-b))) * LOG2E;
    int bd = (combo >> 2) & 1, bh = (combo >> 1) & 1, bw = combo & 1;
    if (maskcode(tokQ, bd, bh, bw) != maskcode(tokK, bd, bh, bw)) v -= 144.269504f;
  }
  rpbf[n] = v;
}

// ---------- prep: pack qkv weights per head: [h][5blk][32][136] bf16 (q_hi,q_lo,k_hi,k_lo,v_hi)
__global__ void pack_wqkv(const float* __restrict__ qkvw, u16* __restrict__ dst) {
  int bid = blockIdx.x;                       // 640 = 4h * 5blk * 32r
  int h = bid / 160, rem = bid % 160, blk = rem / 32, r = rem % 32;
  int srow = (blk < 2 ? 0 : (blk < 4 ? 128 : 256)) + h * 32 + r;
  bool lo = (blk == 1) || (blk == 3);
  int c = threadIdx.x;                        // 0..135
  float v = (c < 128) ? qkvw[srow * 128 + c] : 0.f;
  u16 hi = f2bu_sw(v);
  u16 outv = lo ? f2bu_sw(v - bu2f(hi)) : hi;
  dst[h * 21760 + blk * 4352 + r * 136 + c] = outv;
}

// ---------- prep: pack proj weights [128][136] bf16 (row c = output col) ----------
__global__ void pack_wproj(const float* __restrict__ pw, u16* __restrict__ dst) {
  int c = blockIdx.x;                         // 0..127
  int m = threadIdx.x;                        // 0..135
  float v = (m < 128) ? pw[c * 128 + m] : 0.f;
  dst[c * 136 + m] = f2bu_sw(v);
}

// ---------- attention kernel: one block per (window, head) ----------
// XCD-aware decode: bid = g*32 + h*8 + s ; win = g*8+s, head = h -> all 4 heads of a
// window land on the same XCD (bid % 8 == s), sharing x in that XCD's L2.
// LDS pool 19328 u16 (38656 B) -> 4 blocks/CU:
//   phase1: staged W q/k hi/lo [4][32][136] = 17408 @0  (V weights streamed from L2)
//   phase2/3: Qhi@0, Qlo@4480, Khi@8960, Klo@13440 (each [112][40])
//   phase4: P [112][136] @0 (row-major, stride 136 -> 2-way banks) ; VT [32][128] swz @15232
#define QHI 0
#define QLO 4480
#define KHI 8960
#define KLO 13440
#define PB  0
#define VTB 15232
#define VIDX(d, t) (VTB + (d) * 128 + ((t) ^ (((d) & 7) << 3)))

template <bool BF16OUT>
__global__ __launch_bounds__(448, 7) void swin_attn(
    const float* __restrict__ xg, const float* __restrict__ qkvb,
    const float* __restrict__ lscale, const float* __restrict__ rpbf,
    const u16* __restrict__ wqkv, u16* __restrict__ aoutb, float* __restrict__ aoutf) {
  __shared__ u16 lds[19328];
  const int tid = threadIdx.x;
  const int wv = tid >> 6;
  const int l = tid & 63;
  const int l15 = l & 15;
  const int lg = l >> 4;
  const int bid = blockIdx.x;
  const int win = ((bid >> 5) << 3) | (bid & 7);  // XCD-stable window slot
  const int h = (bid >> 3) & 3;
  const int iw = win & 15, ih = (win >> 4) & 15, id = win >> 8;
  const int combo = ((id == 7) << 2) | ((ih == 15) << 1) | (iw == 15);

  // ---- stage q/k weights (17408 u16 = 2176 uint4) ----
  {
    const uint4* src = (const uint4*)(wqkv + h * 21760);
    uint4* dst = (uint4*)lds;
    for (int it = tid; it < 2176; it += 448) dst[it] = src[it];
  }
  // ---- gather own A-row straight to registers (branchless; pad rows clamp to row 0) ----
  const int arow = 16 * wv + l15;
  bf16x8 xa[4];
  {
    const int base = tokbase((arow < 98) ? arow : 0, id, ih, iw);
    const float* xp = xg + base + lg * 8;
#pragma unroll
    for (int ks = 0; ks < 4; ++ks) {
      const float4 a = *(const float4*)(xp + ks * 32);
      const float4 b4 = *(const float4*)(xp + ks * 32 + 4);
      u16* xo = (u16*)&xa[ks];
      xo[0] = f2b(a.x); xo[1] = f2b(a.y); xo[2] = f2b(a.z); xo[3] = f2b(a.w);
      xo[4] = f2b(b4.x); xo[5] = f2b(b4.y); xo[6] = f2b(b4.z); xo[7] = f2b(b4.w);
    }
  }
  __syncthreads();  // B1: weights staged

  // ---- GEMM1: q,k SWAPPED (D[chan][token]); v standard (D[token][chan]) ----
  const f32x4 zf = {0.f, 0.f, 0.f, 0.f};
  f32x4 aq0 = zf, aq1 = zf, ak0 = zf, ak1 = zf, av0 = zf, av1 = zf;
  const u16* wvb = wqkv + h * 21760 + 17408 + lg * 8;
  bf16x8 bv0 = *(const bf16x8*)(wvb + l15 * 136);
  bf16x8 bv1 = *(const bf16x8*)(wvb + (16 + l15) * 136);
  __builtin_amdgcn_s_setprio(1);
#pragma unroll
  for (int ks = 0; ks < 4; ++ks) {
    const int k0 = ks * 32 + lg * 8;
    bf16x8 nv0, nv1;
    if (ks < 3) {
      nv0 = *(const bf16x8*)(wvb + l15 * 136 + (ks + 1) * 32);
      nv1 = *(const bf16x8*)(wvb + (16 + l15) * 136 + (ks + 1) * 32);
    }
    bf16x8 b;
    b = *(const bf16x8*)(&lds[l15 * 136 + k0]);                aq0 = MFMA(b, xa[ks], aq0);
    b = *(const bf16x8*)(&lds[4352 + l15 * 136 + k0]);         aq0 = MFMA(b, xa[ks], aq0);
    b = *(const bf16x8*)(&lds[(16 + l15) * 136 + k0]);         aq1 = MFMA(b, xa[ks], aq1);
    b = *(const bf16x8*)(&lds[4352 + (16 + l15) * 136 + k0]);  aq1 = MFMA(b, xa[ks], aq1);
    b = *(const bf16x8*)(&lds[8704 + l15 * 136 + k0]);         ak0 = MFMA(b, xa[ks], ak0);
    b = *(const bf16x8*)(&lds[13056 + l15 * 136 + k0]);        ak0 = MFMA(b, xa[ks], ak0);
    b = *(const bf16x8*)(&lds[8704 + (16 + l15) * 136 + k0]);  ak1 = MFMA(b, xa[ks], ak1);
    b = *(const bf16x8*)(&lds[13056 + (16 + l15) * 136 + k0]); ak1 = MFMA(b, xa[ks], ak1);
    av0 = MFMA(xa[ks], bv0, av0);
    av1 = MFMA(xa[ks], bv1, av1);
    if (ks < 3) { bv0 = nv0; bv1 = nv1; }
  }
  __builtin_amdgcn_s_setprio(0);
  __syncthreads();  // B2: weight reads done -> pool reusable

  // ---- rpb C-init prefetch (L2 latency hides under phase2 VALU) ----
  const f32x4* rbf = (const f32x4*)rpbf + (((combo * 4 + h) * 7 + wv) * 7) * 64 + l;
  f32x4 att[7];
#pragma unroll
  for (int c = 0; c < 7; ++c) att[c] = rbf[c * 64];

  // ---- phase2: bias, cosine-normalize; thread owns ONE token x 8 chans ----
  const float sc2 = __expf(fminf(lscale[h], 4.60517019f)) * LOG2E;
  const float4 qb0v = *(const float4*)(qkvb + h * 32 + lg * 4);
  const float4 qb1v = *(const float4*)(qkvb + h * 32 + 16 + lg * 4);
  const float vb0 = qkvb[256 + h * 32 + l15];
  const float vb1 = qkvb[256 + h * 32 + 16 + l15];
  aq0[0] += qb0v.x; aq0[1] += qb0v.y; aq0[2] += qb0v.z; aq0[3] += qb0v.w;
  aq1[0] += qb1v.x; aq1[1] += qb1v.y; aq1[2] += qb1v.z; aq1[3] += qb1v.w;
#pragma unroll
  for (int r = 0; r < 4; ++r) { av0[r] += vb0; av1[r] += vb1; }
  float sq = 0.f, sk = 0.f;
#pragma unroll
  for (int r = 0; r < 4; ++r) {
    sq += aq0[r] * aq0[r] + aq1[r] * aq1[r];
    sk += ak0[r] * ak0[r] + ak1[r] * ak1[r];
  }
  sq += __shfl_xor(sq, 16); sq += __shfl_xor(sq, 32);
  sk += __shfl_xor(sk, 16); sk += __shfl_xor(sk, 32);
  const int tok = 16 * wv + l15;
  const bool ok = tok < 98;
  const float rnq = sc2 * rsqrtf(fmaxf(sq, 1e-24f));
  const float rnk = rsqrtf(fmaxf(sk, 1e-24f));
  {
    ushort4 qh0, qh1, ql0, ql1, kh0, kh1, kl0, kl1;
#pragma unroll
    for (int r = 0; r < 4; ++r) {
      float q0 = ok ? aq0[r] * rnq : 0.f;
      float q1 = ok ? aq1[r] * rnq : 0.f;
      float k0v = ok ? ak0[r] * rnk : 0.f;
      float k1v = ok ? ak1[r] * rnk : 0.f;
      u16 a = f2b(q0); ((u16*)&qh0)[r] = a; ((u16*)&ql0)[r] = f2b(q0 - bu2f(a));
      u16 b2 = f2b(q1); ((u16*)&qh1)[r] = b2; ((u16*)&ql1)[r] = f2b(q1 - bu2f(b2));
      u16 c2 = f2b(k0v); ((u16*)&kh0)[r] = c2; ((u16*)&kl0)[r] = f2b(k0v - bu2f(c2));
      u16 d2 = f2b(k1v); ((u16*)&kh1)[r] = d2; ((u16*)&kl1)[r] = f2b(k1v - bu2f(d2));
    }
    *(ushort4*)(&lds[QHI + tok * 40 + lg * 4]) = qh0;
    *(ushort4*)(&lds[QHI + tok * 40 + 16 + lg * 4]) = qh1;
    *(ushort4*)(&lds[QLO + tok * 40 + lg * 4]) = ql0;
    *(ushort4*)(&lds[QLO + tok * 40 + 16 + lg * 4]) = ql1;
    *(ushort4*)(&lds[KHI + tok * 40 + lg * 4]) = kh0;
    *(ushort4*)(&lds[KHI + tok * 40 + 16 + lg * 4]) = kh1;
    *(ushort4*)(&lds[KLO + tok * 40 + lg * 4]) = kl0;
    *(ushort4*)(&lds[KLO + tok * 40 + 16 + lg * 4]) = kl1;
  }
  __syncthreads();  // B3: Q/K ready

  // ---- phase3: QK^T SWAPPED (D[tokK][tokQ]) with fragment rpb(+mask) as C-init ----
  const bf16x8 qh = *(const bf16x8*)(&lds[QHI + tok * 40 + lg * 8]);
  const bf16x8 qlo = *(const bf16x8*)(&lds[QLO + tok * 40 + lg * 8]);
  __builtin_amdgcn_s_setprio(1);
#pragma unroll
  for (int c = 0; c < 7; ++c) {
    const bf16x8 kh = *(const bf16x8*)(&lds[KHI + (16 * c + l15) * 40 + lg * 8]);
    const bf16x8 kl = *(const bf16x8*)(&lds[KLO + (16 * c + l15) * 40 + lg * 8]);
    att[c] = MFMA(kh, qh, att[c]);
    att[c] = MFMA(kh, qlo, att[c]);
    att[c] = MFMA(kl, qh, att[c]);
  }
  __builtin_amdgcn_s_setprio(0);
  // ---- softmax: per-thread token, in-thread 28-sum + 2 shfls; no max (logits bounded) ----
  float s = 0.f;
#pragma unroll
  for (int c = 0; c < 7; ++c)
#pragma unroll
    for (int r = 0; r < 4; ++r) { float p = exp2f(att[c][r]); att[c][r] = p; s += p; }
  s += __shfl_xor(s, 16); s += __shfl_xor(s, 32);
  const float rsv = 1.0f / s;
  __syncthreads();  // B4: Q/K reads done -> P/VT may overlay

  // ---- phase4: write P UNNORMALIZED (b64, row tokQ, stride 136) + V^T ----
#pragma unroll
  for (int c = 0; c < 7; ++c) {
    ushort4 pk;
#pragma unroll
    for (int r = 0; r < 4; ++r) ((u16*)&pk)[r] = ok ? f2b(att[c][r]) : (u16)0;
    *(ushort4*)(&lds[PB + tok * 136 + 16 * c + lg * 4]) = pk;
  }
  {
    const int t0 = 16 * wv + lg * 4;
    ushort4 v0, v1;
    v0.x = (t0 + 0 < 98) ? f2b(av0[0]) : (u16)0;
    v0.y = (t0 + 1 < 98) ? f2b(av0[1]) : (u16)0;
    v0.z = (t0 + 2 < 98) ? f2b(av0[2]) : (u16)0;
    v0.w = (t0 + 3 < 98) ? f2b(av0[3]) : (u16)0;
    v1.x = (t0 + 0 < 98) ? f2b(av1[0]) : (u16)0;
    v1.y = (t0 + 1 < 98) ? f2b(av1[1]) : (u16)0;
    v1.z = (t0 + 2 < 98) ? f2b(av1[2]) : (u16)0;
    v1.w = (t0 + 3 < 98) ? f2b(av1[3]) : (u16)0;
    *(ushort4*)(&lds[VIDX(l15, t0)]) = v0;
    *(ushort4*)(&lds[VIDX(16 + l15, t0)]) = v1;
  }
  for (int it = tid; it < 32 * 16; it += 448) {  // zero V^T tok 112..127
    int dd = it >> 4, t = 112 + (it & 15);
    lds[VIDX(dd, t)] = 0;
  }
  __syncthreads();  // B5: P/V^T ready

  // ---- PV TRANSPOSED: D[row=d][col=token]; rsv applied at store (own token) ----
  f32x4 o0 = zf, o1 = zf;
  __builtin_amdgcn_s_setprio(1);
#pragma unroll
  for (int ks = 0; ks < 4; ++ks) {
    const int t = ks * 32 + lg * 8;
    const bf16x8 pb = *(const bf16x8*)(&lds[PB + tok * 136 + t]);
    const bf16x8 v0f = *(const bf16x8*)(&lds[VIDX(l15, t)]);
    const bf16x8 v1f = *(const bf16x8*)(&lds[VIDX(16 + l15, t)]);
    o0 = MFMA(v0f, pb, o0);   // rows d=lg*4+r (0..15), cols token=16wv+l15
    o1 = MFMA(v1f, pb, o1);   // rows d=16+lg*4+r
  }
  __builtin_amdgcn_s_setprio(0);
  if (ok) {
    if (BF16OUT) {
      u16* ab = aoutb + (win * 98 + tok) * 128 + h * 32;
      ushort4 s0, s1;
      s0.x = f2b(o0[0] * rsv); s0.y = f2b(o0[1] * rsv);
      s0.z = f2b(o0[2] * rsv); s0.w = f2b(o0[3] * rsv);
      s1.x = f2b(o1[0] * rsv); s1.y = f2b(o1[1] * rsv);
      s1.z = f2b(o1[2] * rsv); s1.w = f2b(o1[3] * rsv);
      *(ushort4*)(ab + lg * 4) = s0;
      *(ushort4*)(ab + 16 + lg * 4) = s1;
    } else {
      float* ab = aoutf + tokbase(tok, id, ih, iw) + h * 32;
      f32x4 s0, s1;
#pragma unroll
      for (int r = 0; r < 4; ++r) { s0[r] = o0[r] * rsv; s1[r] = o1[r] * rsv; }
      *(f32x4*)(ab + lg * 4) = s0;
      *(f32x4*)(ab + 16 + lg * 4) = s1;
    }
  }
}

// ---------- proj kernel: one block per window, transposed MFMA ----------
template <bool BF16OUT>
__global__ __launch_bounds__(448, 7) void swin_proj(const u16* __restrict__ wp,
                                                    const float* __restrict__ projb,
                                                    const u16* __restrict__ aoutb,
                                                    float* io) {
  __shared__ u16 w[17408];
  __shared__ int tb[98];
  const int tid = threadIdx.x;
  const int wv = tid >> 6;
  const int l = tid & 63;
  const int l15 = l & 15;
  const int lg = l >> 4;
  const int win = blockIdx.x;
  const int iw = win & 15, ih = (win >> 4) & 15, id = win >> 8;
  if (tid < 98) tb[tid] = tokbase(tid, id, ih, iw);
  {
    const uint4* src = (const uint4*)wp;
    uint4* dst = (uint4*)w;
    for (int it = tid; it < 2176; it += 448) dst[it] = src[it];
  }
  __syncthreads();
  const int tok = 16 * wv + l15;
  const int tokc = (tok < 98) ? tok : 97;

  const f32x4 zf = {0.f, 0.f, 0.f, 0.f};
  f32x4 pr[8];
#pragma unroll
  for (int n = 0; n < 8; ++n) pr[n] = zf;
#pragma unroll
  for (int ks = 0; ks < 4; ++ks) {
    bf16x8 oa;  // B-operand: rows = tokens
    if (BF16OUT) {
      oa = *(const bf16x8*)(aoutb + (win * 98 + tokc) * 128 + ks * 32 + lg * 8);
    } else {
      const float* ap = io + tb[tokc] + ks * 32 + lg * 8;
      const float4 f0 = *(const float4*)(ap);
      const float4 f1 = *(const float4*)(ap + 4);
      u16* op = (u16*)&oa;
      op[0] = f2b(f0.x); op[1] = f2b(f0.y); op[2] = f2b(f0.z); op[3] = f2b(f0.w);
      op[4] = f2b(f1.x); op[5] = f2b(f1.y); op[6] = f2b(f1.z); op[7] = f2b(f1.w);
    }
#pragma unroll
    for (int n = 0; n < 8; ++n) {
      const bf16x8 wbf = *(const bf16x8*)(&w[(16 * n + l15) * 136 + ks * 32 + lg * 8]);
      pr[n] = MFMA(wbf, oa, pr[n]);  // rows = outcols 16n+lg*4+r, cols = token l15
    }
  }
  // store: lane holds 4 consecutive outcols of its token -> float4 scatter per row
#pragma unroll
  for (int n = 0; n < 8; ++n) {
    const float4 pb4 = *(const float4*)(projb + 16 * n + lg * 4);
    f32x4 o = pr[n];
    o[0] += pb4.x; o[1] += pb4.y; o[2] += pb4.z; o[3] += pb4.w;
    if (tok < 98) *(f32x4*)(io + tb[tok] + 16 * n + lg * 4) = o;
  }
}

extern "C" void kernel_launch(void* const* d_in, const int* in_sizes, int n_in,
                              void* d_out, int out_size, void* d_ws, size_t ws_size,
                              hipStream_t stream) {
  const float* xg = (const float*)d_in[0];
  const float* qkvw = (const float*)d_in[1];
  const float* qkvb = (const float*)d_in[2];
  const float* projw = (const float*)d_in[3];
  const float* projb = (const float*)d_in[4];
  const float* lsc = (const float*)d_in[5];
  const float* w1 = (const float*)d_in[6];
  const float* b1 = (const float*)d_in[7];
  const float* w2 = (const float*)d_in[8];

  char* ws = (char*)d_ws;
  float* btab = (float*)(ws);             // 8,112 B
  u16* wq = (u16*)(ws + 8192);            // 174,080 B -> ends 182,272
  u16* wp = (u16*)(ws + 182272);          // 34,816 B  -> ends 217,088
  float* rpbf = (float*)(ws + 217088);    // 1,605,632 B -> ends 1,822,720
  u16* aoutb = (u16*)(ws + 1822720);      // 51,380,224 B -> ends 53,202,944
  float* io = (float*)d_out;

  const bool bf16path = ws_size >= (size_t)53202944;

  cpb_mlp<<<507, 512, 0, stream>>>(w1, b1, w2, btab);
  build_rpbf<<<(8 * 4 * 7 * 7 * 64 * 4 + 255) / 256, 256, 0, stream>>>(btab, rpbf);
  pack_wqkv<<<640, 136, 0, stream>>>(qkvw, wq);
  pack_wproj<<<128, 136, 0, stream>>>(projw, wp);
  if (bf16path) {
    swin_attn<true><<<8192, 448, 0, stream>>>(xg, qkvb, lsc, rpbf, wq, aoutb, io);
    swin_proj<true><<<2048, 448, 0, stream>>>(wp, projb, aoutb, io);
  } else {
    swin_attn<false><<<8192, 448, 0, stream>>>(xg, qkvb, lsc, rpbf, wq, nullptr, io);
    swin_proj<false><<<2048, 448, 0, stream>>>(wp, projb, nullptr, io);
  }
}